// Round 4
// baseline (2130.785 us; speedup 1.0000x reference)
//
#include <hip/hip_runtime.h>

typedef short short8 __attribute__((ext_vector_type(8)));
typedef float f32x4 __attribute__((ext_vector_type(4)));

#define N_NODES 100000
#define N_EDGES 1600000
#define D_IN 256
#define D_OUT 128

#define BSHIFT 7
#define BROWS 128            // rows per bucket
#define NBUCK 782            // ceil(100000/128)

// ws layout (bytes)
#define OFF_H     0UL          // bf16 h: 100000*128*2 = 25,600,000
#define OFF_WP    25600000UL   // packed W bf16 fragments: 65,536
#define OFF_BCNT  25665536UL   // int[NBUCK] bucket counts (pad 4096)
#define OFF_BOFF  25669632UL   // int[NBUCK+1] bucket offsets (pad 4096)
#define OFF_BCUR  25673728UL   // int[NBUCK] bucket cursors (pad 4096)
#define OFF_BPEV  25677824UL   // uint2[1.6M] binned (col|rowlo<<17, val) = 12,800,000
// total ~38.5 MB

__device__ __forceinline__ unsigned short f2bf(float f) {
    unsigned int u = __builtin_bit_cast(unsigned int, f);
    u += 0x7fffu + ((u >> 16) & 1u);   // RNE
    return (unsigned short)(u >> 16);
}

// Pack W [256][128] fp32 -> bf16 MFMA B-fragments.
// idx t = ks*512 + nt*64 + lane, elems e=0..7 at k=ks*32+(lane>>4)*8+e, n=nt*16+(lane&15)
__global__ void wpack_k(const float* __restrict__ W, unsigned short* __restrict__ wp) {
    int t = blockIdx.x * 256 + threadIdx.x;
    if (t >= 4096) return;
    int ks = t >> 9, nt = (t >> 6) & 7, lane = t & 63;
    int g = lane >> 4, n = nt * 16 + (lane & 15);
    int k0 = ks * 32 + g * 8;
#pragma unroll
    for (int e = 0; e < 8; ++e)
        wp[t * 8 + e] = f2bf(W[(size_t)(k0 + e) * D_OUT + n]);
}

// h = bf16( x @ W + b ), one 16-row tile per wave, full N=128 in registers.
__global__ __launch_bounds__(256) void gemm_k(const float* __restrict__ x,
                                              const short8* __restrict__ wq,
                                              const float* __restrict__ b,
                                              unsigned short* __restrict__ h) {
    int wave = threadIdx.x >> 6, lane = threadIdx.x & 63;
    int tile = blockIdx.x * 4 + wave;
    if (tile * 16 >= N_NODES) return;
    int row0 = tile * 16;
    int r = lane & 15, g = lane >> 4;

    f32x4 acc[8];
#pragma unroll
    for (int nt = 0; nt < 8; ++nt)
#pragma unroll
        for (int j = 0; j < 4; ++j) acc[nt][j] = 0.f;

    float bv[8];
#pragma unroll
    for (int nt = 0; nt < 8; ++nt) bv[nt] = b[nt * 16 + r];

    const float4* xp = (const float4*)(x + (size_t)(row0 + r) * D_IN);
#pragma unroll
    for (int ks = 0; ks < 8; ++ks) {
        float4 u0 = xp[ks * 8 + g * 2];
        float4 u1 = xp[ks * 8 + g * 2 + 1];
        short8 af;
        af[0] = (short)f2bf(u0.x); af[1] = (short)f2bf(u0.y);
        af[2] = (short)f2bf(u0.z); af[3] = (short)f2bf(u0.w);
        af[4] = (short)f2bf(u1.x); af[5] = (short)f2bf(u1.y);
        af[6] = (short)f2bf(u1.z); af[7] = (short)f2bf(u1.w);
#pragma unroll
        for (int nt = 0; nt < 8; ++nt) {
            short8 bf = wq[(ks * 8 + nt) * 64 + lane];
            acc[nt] = __builtin_amdgcn_mfma_f32_16x16x32_bf16(af, bf, acc[nt], 0, 0, 0);
        }
    }
#pragma unroll
    for (int nt = 0; nt < 8; ++nt)
#pragma unroll
        for (int j = 0; j < 4; ++j) {
            float v = acc[nt][j] + bv[nt];
            h[(size_t)(row0 + g * 4 + j) * D_OUT + nt * 16 + r] = f2bf(v);
        }
}

// Per-bucket histogram, 4 edges/thread, fire-and-forget atomics on 782 counters.
__global__ void bcount_k(const int4* __restrict__ er4, int* __restrict__ bcnt) {
    int t = blockIdx.x * 256 + threadIdx.x;
    if (t >= N_EDGES / 4) return;
    int4 r = er4[t];
    atomicAdd(&bcnt[r.x >> BSHIFT], 1);
    atomicAdd(&bcnt[r.y >> BSHIFT], 1);
    atomicAdd(&bcnt[r.z >> BSHIFT], 1);
    atomicAdd(&bcnt[r.w >> BSHIFT], 1);
}

// Single-block exclusive scan over NBUCK (<=1024) counters -> boffs + cursor copy.
__global__ __launch_bounds__(1024) void bscan_k(const int* __restrict__ bcnt,
                                                int* __restrict__ boffs,
                                                int* __restrict__ bcur) {
    __shared__ int s[1024];
    int t = threadIdx.x;
    int v = (t < NBUCK) ? bcnt[t] : 0;
    s[t] = v;
    __syncthreads();
    for (int off = 1; off < 1024; off <<= 1) {
        int tmp = (t >= off) ? s[t - off] : 0;
        __syncthreads();
        s[t] += tmp;
        __syncthreads();
    }
    if (t < NBUCK) {
        int excl = s[t] - v;
        boffs[t] = excl;
        bcur[t] = excl;
    }
    if (t == 0) boffs[NBUCK] = N_EDGES;
}

// Bin edges by bucket: global cursor per bucket -> adjacent slots -> dense line fill.
__global__ void bin_k(const int4* __restrict__ er4, const int4* __restrict__ ec4,
                      const float4* __restrict__ ev4,
                      int* __restrict__ bcur, uint2* __restrict__ bpev) {
    int t = blockIdx.x * 256 + threadIdx.x;
    if (t >= N_EDGES / 4) return;
    int4 r = er4[t];
    int4 c = ec4[t];
    float4 v = ev4[t];
    int rows[4] = {r.x, r.y, r.z, r.w};
    int cols[4] = {c.x, c.y, c.z, c.w};
    float vals[4] = {v.x, v.y, v.z, v.w};
    int pos[4];
#pragma unroll
    for (int i = 0; i < 4; ++i) pos[i] = atomicAdd(&bcur[rows[i] >> BSHIFT], 1);
#pragma unroll
    for (int i = 0; i < 4; ++i) {
        uint2 p;
        p.x = (unsigned int)cols[i] | ((unsigned int)(rows[i] & (BROWS - 1)) << 17);
        p.y = __builtin_bit_cast(unsigned int, vals[i]);
        bpev[pos[i]] = p;
    }
}

// One block per bucket: accumulate 128 rows x 128 cols in LDS (f32 atomics),
// gathering h[col]; stream out relu'd tile coalesced.
__global__ __launch_bounds__(256) void agg_k(const unsigned int* __restrict__ h32,
                                             const int* __restrict__ boffs,
                                             const uint2* __restrict__ bpev,
                                             float* __restrict__ out) {
    __shared__ float acc[BROWS * 128];  // 64 KB
    for (int i = threadIdx.x; i < BROWS * 128 / 4; i += 256) {
        float4 z = {0.f, 0.f, 0.f, 0.f};
        reinterpret_cast<float4*>(acc)[i] = z;
    }
    __syncthreads();

    int b = blockIdx.x;
    int s = boffs[b], e = boffs[b + 1];
    int wave = threadIdx.x >> 6, lane = threadIdx.x & 63;

    for (int base = s + wave * 8; base < e; base += 32) {
        uint2 p[8];
#pragma unroll
        for (int j = 0; j < 8; ++j) {
            int idx = base + j;
            if (idx < e) p[j] = bpev[idx];
            else { p[j].x = 0u; p[j].y = 0u; }  // val=0 -> no-op add
        }
        unsigned int hv[8];
#pragma unroll
        for (int j = 0; j < 8; ++j)
            hv[j] = h32[(size_t)(p[j].x & 0x1FFFFu) * 64 + lane];
#pragma unroll
        for (int j = 0; j < 8; ++j) {
            float v = __builtin_bit_cast(float, p[j].y);
            int rl = (int)(p[j].x >> 17);
            float lo = __builtin_bit_cast(float, hv[j] << 16);
            float hi = __builtin_bit_cast(float, hv[j] & 0xffff0000u);
            atomicAdd(&acc[rl * 128 + lane * 2], v * lo);
            atomicAdd(&acc[rl * 128 + lane * 2 + 1], v * hi);
        }
    }
    __syncthreads();

    int row0 = b << BSHIFT;
    for (int i = threadIdx.x; i < BROWS * 32; i += 256) {
        int r = i >> 5, c4 = i & 31;
        int row = row0 + r;
        if (row < N_NODES) {
            float4 t4 = reinterpret_cast<float4*>(acc)[i];
            t4.x = fmaxf(t4.x, 0.f);
            t4.y = fmaxf(t4.y, 0.f);
            t4.z = fmaxf(t4.z, 0.f);
            t4.w = fmaxf(t4.w, 0.f);
            reinterpret_cast<float4*>(out + (size_t)row * 128)[c4] = t4;
        }
    }
}

extern "C" void kernel_launch(void* const* d_in, const int* in_sizes, int n_in,
                              void* d_out, int out_size, void* d_ws, size_t ws_size,
                              hipStream_t stream) {
    const float* x = (const float*)d_in[0];
    const float* W = (const float*)d_in[1];
    const float* b = (const float*)d_in[2];
    const int* er = (const int*)d_in[3];
    const int* ec = (const int*)d_in[4];
    const float* ev = (const float*)d_in[5];
    float* out = (float*)d_out;
    char* ws = (char*)d_ws;

    unsigned short* h = (unsigned short*)(ws + OFF_H);
    unsigned short* wp = (unsigned short*)(ws + OFF_WP);
    int* bcnt = (int*)(ws + OFF_BCNT);
    int* boffs = (int*)(ws + OFF_BOFF);
    int* bcur = (int*)(ws + OFF_BCUR);
    uint2* bpev = (uint2*)(ws + OFF_BPEV);

    hipMemsetAsync(bcnt, 0, 4096, stream);

    wpack_k<<<16, 256, 0, stream>>>(W, wp);
    gemm_k<<<1563, 256, 0, stream>>>(x, (const short8*)wp, b, h);
    bcount_k<<<(N_EDGES / 4 + 255) / 256, 256, 0, stream>>>((const int4*)er, bcnt);
    bscan_k<<<1, 1024, 0, stream>>>(bcnt, boffs, bcur);
    bin_k<<<(N_EDGES / 4 + 255) / 256, 256, 0, stream>>>((const int4*)er, (const int4*)ec,
                                                         (const float4*)ev, bcur, bpev);
    agg_k<<<NBUCK, 256, 0, stream>>>((const unsigned int*)h, boffs, bpev, out);
}

// Round 5
// 311.598 us; speedup vs baseline: 6.8382x; 6.8382x over previous
//
#include <hip/hip_runtime.h>

typedef short short8 __attribute__((ext_vector_type(8)));
typedef float f32x4 __attribute__((ext_vector_type(4)));

#define N_NODES 100000
#define N_EDGES 1600000
#define D_IN 256
#define D_OUT 128

// ws layout (bytes). cnt overlays the pev region: cnt is dead after scan3,
// pev is only written in scatter_k (after scan3). Padded cursors (stride-16
// ints = one 64B line per counter) need ~45.3 MB; fallback stride-1 needs ~39.3 MB.
#define OFF_H     0UL          // bf16 h: 25,600,000
#define OFF_WP    25600000UL   // packed W: 65,536
#define OFF_OFFS  25665536UL   // int[100001] row offsets: 400,016
#define OFF_BS    26065552UL   // int[1024] block sums: 4,096
#define OFF_PEV   26069648UL   // uint2[1.6M]: 12,800,000  (cnt overlays start of this)
#define OFF_CNT   OFF_PEV      // int[100000*str]
#define OFF_MUT   38869648UL   // int[100000*str] cursors
#define WS_PAD_NEEDED (OFF_MUT + 100000UL * 16 * 4)
#define WS_MIN_NEEDED (OFF_MUT + 100000UL * 4)

__device__ __forceinline__ unsigned short f2bf(float f) {
    unsigned int u = __builtin_bit_cast(unsigned int, f);
    u += 0x7fffu + ((u >> 16) & 1u);   // RNE
    return (unsigned short)(u >> 16);
}

// Pack W [256][128] fp32 -> bf16 MFMA B-fragments.
__global__ void wpack_k(const float* __restrict__ W, unsigned short* __restrict__ wp) {
    int t = blockIdx.x * 256 + threadIdx.x;
    if (t >= 4096) return;
    int ks = t >> 9, nt = (t >> 6) & 7, lane = t & 63;
    int g = lane >> 4, n = nt * 16 + (lane & 15);
    int k0 = ks * 32 + g * 8;
#pragma unroll
    for (int e = 0; e < 8; ++e)
        wp[t * 8 + e] = f2bf(W[(size_t)(k0 + e) * D_OUT + n]);
}

// h = bf16( x @ W + b ), one 16-row tile per wave, full N=128 in registers.
__global__ __launch_bounds__(256) void gemm_k(const float* __restrict__ x,
                                              const short8* __restrict__ wq,
                                              const float* __restrict__ b,
                                              unsigned short* __restrict__ h) {
    int wave = threadIdx.x >> 6, lane = threadIdx.x & 63;
    int tile = blockIdx.x * 4 + wave;
    if (tile * 16 >= N_NODES) return;
    int row0 = tile * 16;
    int r = lane & 15, g = lane >> 4;

    f32x4 acc[8];
#pragma unroll
    for (int nt = 0; nt < 8; ++nt)
#pragma unroll
        for (int j = 0; j < 4; ++j) acc[nt][j] = 0.f;

    float bv[8];
#pragma unroll
    for (int nt = 0; nt < 8; ++nt) bv[nt] = b[nt * 16 + r];

    const float4* xp = (const float4*)(x + (size_t)(row0 + r) * D_IN);
#pragma unroll
    for (int ks = 0; ks < 8; ++ks) {
        float4 u0 = xp[ks * 8 + g * 2];
        float4 u1 = xp[ks * 8 + g * 2 + 1];
        short8 af;
        af[0] = (short)f2bf(u0.x); af[1] = (short)f2bf(u0.y);
        af[2] = (short)f2bf(u0.z); af[3] = (short)f2bf(u0.w);
        af[4] = (short)f2bf(u1.x); af[5] = (short)f2bf(u1.y);
        af[6] = (short)f2bf(u1.z); af[7] = (short)f2bf(u1.w);
#pragma unroll
        for (int nt = 0; nt < 8; ++nt) {
            short8 bf = wq[(ks * 8 + nt) * 64 + lane];
            acc[nt] = __builtin_amdgcn_mfma_f32_16x16x32_bf16(af, bf, acc[nt], 0, 0, 0);
        }
    }
#pragma unroll
    for (int nt = 0; nt < 8; ++nt)
#pragma unroll
        for (int j = 0; j < 4; ++j) {
            float v = acc[nt][j] + bv[nt];
            h[(size_t)(row0 + g * 4 + j) * D_OUT + nt * 16 + r] = f2bf(v);
        }
}

// 4 edges/thread, fire-and-forget atomics on line-padded counters.
__global__ void count_k(const int4* __restrict__ er4, int* __restrict__ cnt, int str) {
    int t = blockIdx.x * 256 + threadIdx.x;
    if (t >= N_EDGES / 4) return;
    int4 r = er4[t];
    atomicAdd(&cnt[r.x * str], 1);
    atomicAdd(&cnt[r.y * str], 1);
    atomicAdd(&cnt[r.z * str], 1);
    atomicAdd(&cnt[r.w * str], 1);
}

// Hillis-Steele inclusive scan per 1024-block over strided counters.
__global__ __launch_bounds__(1024) void scan1_k(const int* __restrict__ cnt, int* __restrict__ offs,
                                                int* __restrict__ bs, int n, int str) {
    __shared__ int s[1024];
    int t = threadIdx.x;
    int i = blockIdx.x * 1024 + t;
    int v = (i < n) ? cnt[i * str] : 0;
    s[t] = v;
    __syncthreads();
    for (int off = 1; off < 1024; off <<= 1) {
        int tmp = (t >= off) ? s[t - off] : 0;
        __syncthreads();
        s[t] += tmp;
        __syncthreads();
    }
    if (i < n) offs[i] = s[t];
    if (t == 1023) bs[blockIdx.x] = s[1023];
}

__global__ void scan2_k(int* __restrict__ bs, int nb) {
    if (blockIdx.x == 0 && threadIdx.x == 0) {
        int run = 0;
        for (int bb = 0; bb < nb; ++bb) { int t = bs[bb]; bs[bb] = run; run += t; }
        bs[nb] = run;
    }
}

// inclusive->exclusive + block base; dense offs AND line-padded cursor copy.
__global__ void scan3_k(int* __restrict__ offs, const int* __restrict__ cnt,
                        const int* __restrict__ bs, int* __restrict__ offs_mut,
                        int n, int nb, int str) {
    int i = blockIdx.x * 256 + threadIdx.x;
    if (i < n) {
        int v = offs[i] - cnt[i * str] + bs[i >> 10];
        offs[i] = v;
        offs_mut[i * str] = v;
    }
    if (i == 0) offs[n] = bs[nb];
}

// 1 edge/thread (R2 structure), atomic on line-padded cursor.
__global__ void scatter_k(const int* __restrict__ er, const int* __restrict__ ec,
                          const float* __restrict__ ev,
                          int* __restrict__ offs_mut, uint2* __restrict__ pev, int str) {
    int e = blockIdx.x * 256 + threadIdx.x;
    if (e >= N_EDGES) return;
    int rrow = er[e];
    int pos = atomicAdd(&offs_mut[rrow * str], 1);
    uint2 p;
    p.x = (unsigned int)ec[e];
    p.y = __builtin_bit_cast(unsigned int, ev[e]);
    pev[pos] = p;
}

// One wave per output row, 8-deep unrolled gather (unchanged from R2).
__global__ __launch_bounds__(256) void row_k(const unsigned int* __restrict__ h32,
                                             const int* __restrict__ offs,
                                             const uint2* __restrict__ pev,
                                             float* __restrict__ out) {
    int gw = (blockIdx.x * 256 + threadIdx.x) >> 6;
    int lane = threadIdx.x & 63;
    if (gw >= N_NODES) return;
    int s = offs[gw], e2 = offs[gw + 1];
    float accA[4] = {0.f, 0.f, 0.f, 0.f};
    float accB[4] = {0.f, 0.f, 0.f, 0.f};
    int e = s;
    for (; e + 8 <= e2; e += 8) {
        uint2 p[8];
#pragma unroll
        for (int i = 0; i < 8; ++i) p[i] = pev[e + i];
        unsigned int hv[8];
#pragma unroll
        for (int i = 0; i < 8; ++i) hv[i] = h32[(size_t)p[i].x * 64 + lane];
#pragma unroll
        for (int i = 0; i < 8; ++i) {
            float v = __builtin_bit_cast(float, p[i].y);
            accA[i & 3] += v * __builtin_bit_cast(float, hv[i] << 16);
            accB[i & 3] += v * __builtin_bit_cast(float, hv[i] & 0xffff0000u);
        }
    }
    for (; e < e2; ++e) {
        uint2 p = pev[e];
        float v = __builtin_bit_cast(float, p.y);
        unsigned int hv = h32[(size_t)p.x * 64 + lane];
        accA[0] += v * __builtin_bit_cast(float, hv << 16);
        accB[0] += v * __builtin_bit_cast(float, hv & 0xffff0000u);
    }
    float a = (accA[0] + accA[1]) + (accA[2] + accA[3]);
    float bb = (accB[0] + accB[1]) + (accB[2] + accB[3]);
    float2 o;
    o.x = a > 0.f ? a : 0.f;
    o.y = bb > 0.f ? bb : 0.f;
    reinterpret_cast<float2*>(out)[(size_t)gw * 64 + lane] = o;
}

extern "C" void kernel_launch(void* const* d_in, const int* in_sizes, int n_in,
                              void* d_out, int out_size, void* d_ws, size_t ws_size,
                              hipStream_t stream) {
    const float* x = (const float*)d_in[0];
    const float* W = (const float*)d_in[1];
    const float* b = (const float*)d_in[2];
    const int* er = (const int*)d_in[3];
    const int* ec = (const int*)d_in[4];
    const float* ev = (const float*)d_in[5];
    float* out = (float*)d_out;
    char* ws = (char*)d_ws;

    // line-pad atomic counters if scratch allows; else exact R2 behavior
    const int str = (ws_size >= WS_PAD_NEEDED) ? 16 : 1;

    unsigned short* h = (unsigned short*)(ws + OFF_H);
    unsigned short* wp = (unsigned short*)(ws + OFF_WP);
    int* offs = (int*)(ws + OFF_OFFS);
    int* bs = (int*)(ws + OFF_BS);
    int* cnt = (int*)(ws + OFF_CNT);
    int* offs_mut = (int*)(ws + OFF_MUT);
    uint2* pev = (uint2*)(ws + OFF_PEV);

    hipMemsetAsync(cnt, 0, (size_t)100000 * str * 4, stream);

    wpack_k<<<16, 256, 0, stream>>>(W, wp);
    gemm_k<<<1563, 256, 0, stream>>>(x, (const short8*)wp, b, h);
    count_k<<<(N_EDGES / 4 + 255) / 256, 256, 0, stream>>>((const int4*)er, cnt, str);
    scan1_k<<<98, 1024, 0, stream>>>(cnt, offs, bs, N_NODES, str);
    scan2_k<<<1, 64, 0, stream>>>(bs, 98);
    scan3_k<<<(N_NODES + 255) / 256, 256, 0, stream>>>(offs, cnt, bs, offs_mut, N_NODES, 98, str);
    scatter_k<<<(N_EDGES + 255) / 256, 256, 0, stream>>>(er, ec, ev, offs_mut, pev, str);
    row_k<<<(N_NODES * 64) / 256, 256, 0, stream>>>((const unsigned int*)h, offs, pev, out);
}